// Round 1
// baseline (1182.394 us; speedup 1.0000x reference)
//
#include <hip/hip_runtime.h>

#define T_LEN 1024
#define B_TOTAL 8192
#define H 32

__device__ __forceinline__ float fast_tanh(float x) {
    // tanh(x) = 1 - 2/(exp(2x)+1); exp via v_exp_f32, div via v_rcp_f32.
    float e = __builtin_amdgcn_exp2f(x * 2.8853900817779268f); // 2*log2(e)
    float r = __builtin_amdgcn_rcpf(e + 1.0f);
    return fmaf(-2.0f, r, 1.0f);
}

// One 32-lane group per batch element; lane i owns hidden unit i.
// 256 threads = 8 groups per block; grid = B/8 = 1024 blocks.
__global__ __launch_bounds__(256, 2) void rnn_fused_kernel(
    const float* __restrict__ x,     const float* __restrict__ h0,
    const float* __restrict__ W_ih0, const float* __restrict__ W_hh0,
    const float* __restrict__ b_ih0, const float* __restrict__ b_hh0,
    const float* __restrict__ W_ih1, const float* __restrict__ W_hh1,
    const float* __restrict__ b_ih1, const float* __restrict__ b_hh1,
    const float* __restrict__ W_out, const float* __restrict__ b_out,
    float* __restrict__ out)
{
    // pad group stride to 72 floats (288B): groups in the same wave land on
    // disjoint bank spans (8-bank rotation) -> conflict-free b128 broadcasts.
    __shared__ __align__(16) float hb[8][2][36];

    const int g = threadIdx.x >> 5;   // group (batch) within block
    const int i = threadIdx.x & 31;   // hidden unit owned by this lane
    const int b = blockIdx.x * 8 + g; // batch element

    // --- load per-lane weight rows into registers (one-time) ---
    float w0[32], w1[32], w2[32];
#pragma unroll
    for (int k = 0; k < 8; ++k) {
        ((float4*)w0)[k] = ((const float4*)(W_hh0 + i * 32))[k];
        ((float4*)w1)[k] = ((const float4*)(W_ih1 + i * 32))[k];
        ((float4*)w2)[k] = ((const float4*)(W_hh1 + i * 32))[k];
    }
    const float wih0 = W_ih0[i];
    const float c0 = b_ih0[i] + b_hh0[i];
    const float c1 = b_ih1[i] + b_hh1[i];
    const float wo = W_out[i];
    const float bo = b_out[0];

    // --- replicated hidden state (all 32 values in every lane) ---
    float h1rep[32], h2rep[32];
#pragma unroll
    for (int k = 0; k < 8; ++k) {
        ((float4*)h1rep)[k] = ((const float4*)(h0 + (size_t)b * 32))[k];
        ((float4*)h2rep)[k] = ((const float4*)(h0 + (size_t)(B_TOTAL + b) * 32))[k];
    }

    const float* xp = x + (size_t)b * T_LEN;
    float* yp = out + (size_t)b * T_LEN;
    float h1c = 0.0f, h2c = 0.0f; // this lane's own current h elements

    for (int t = 0; t < T_LEN; t += 4) {
        const float4 xv = *(const float4*)(xp + t);
        float y0, y1, y2, y3;
#pragma unroll
        for (int u = 0; u < 4; ++u) {
            const float xt = (u == 0) ? xv.x : (u == 1) ? xv.y : (u == 2) ? xv.z : xv.w;

            // ---- layer 1: a = c0 + x*wih0 + W_hh0[i,:] . h1 ----
            float a0 = fmaf(xt, wih0, c0), a1 = 0.f, a2 = 0.f, a3 = 0.f;
#pragma unroll
            for (int j = 0; j < 32; j += 4) {
                a0 = fmaf(w0[j + 0], h1rep[j + 0], a0);
                a1 = fmaf(w0[j + 1], h1rep[j + 1], a1);
                a2 = fmaf(w0[j + 2], h1rep[j + 2], a2);
                a3 = fmaf(w0[j + 3], h1rep[j + 3], a3);
            }
            h1c = fast_tanh((a0 + a1) + (a2 + a3));
            hb[g][0][i] = h1c; // publish own element

            // ---- layer 2 partial with OLD h2 (hides h1 LDS round-trip) ----
            float d0 = c1, d1 = 0.f, d2 = 0.f, d3 = 0.f;
#pragma unroll
            for (int j = 0; j < 32; j += 4) {
                d0 = fmaf(w2[j + 0], h2rep[j + 0], d0);
                d1 = fmaf(w2[j + 1], h2rep[j + 1], d1);
                d2 = fmaf(w2[j + 2], h2rep[j + 2], d2);
                d3 = fmaf(w2[j + 3], h2rep[j + 3], d3);
            }

            // ---- re-replicate h1 (wave-internal LDS FIFO; no barrier) ----
#pragma unroll
            for (int k = 0; k < 8; ++k)
                ((float4*)h1rep)[k] = ((const float4*)&hb[g][0][0])[k];

#pragma unroll
            for (int j = 0; j < 32; j += 4) {
                d0 = fmaf(w1[j + 0], h1rep[j + 0], d0);
                d1 = fmaf(w1[j + 1], h1rep[j + 1], d1);
                d2 = fmaf(w1[j + 2], h1rep[j + 2], d2);
                d3 = fmaf(w1[j + 3], h1rep[j + 3], d3);
            }
            h2c = fast_tanh((d0 + d1) + (d2 + d3));
            hb[g][1][i] = h2c;

            // ---- y = W_out . h2_new + b_out (partial + xor-reduce) ----
            float p = wo * h2c;
            p += __shfl_xor(p, 1);
            p += __shfl_xor(p, 2);
            p += __shfl_xor(p, 4);
            p += __shfl_xor(p, 8);
            p += __shfl_xor(p, 16);
            const float yv = p + bo;
            if (u == 0) y0 = yv; else if (u == 1) y1 = yv; else if (u == 2) y2 = yv; else y3 = yv;

            // ---- re-replicate h2 for next step (hidden under next matvec1) ----
#pragma unroll
            for (int k = 0; k < 8; ++k)
                ((float4*)h2rep)[k] = ((const float4*)&hb[g][1][0])[k];
        }
        if (i == 0) {
            float4 yo; yo.x = y0; yo.y = y1; yo.z = y2; yo.w = y3;
            *(float4*)(yp + t) = yo;
        }
    }

    // final hidden states: h_state [2, B, 32]
    out[(size_t)B_TOTAL * T_LEN + (size_t)b * 32 + i] = h1c;
    out[(size_t)B_TOTAL * T_LEN + (size_t)(B_TOTAL + b) * 32 + i] = h2c;
}

extern "C" void kernel_launch(void* const* d_in, const int* in_sizes, int n_in,
                              void* d_out, int out_size, void* d_ws, size_t ws_size,
                              hipStream_t stream) {
    const float* x     = (const float*)d_in[0];
    const float* h0    = (const float*)d_in[1];
    const float* W_ih0 = (const float*)d_in[2];
    const float* W_hh0 = (const float*)d_in[3];
    const float* b_ih0 = (const float*)d_in[4];
    const float* b_hh0 = (const float*)d_in[5];
    const float* W_ih1 = (const float*)d_in[6];
    const float* W_hh1 = (const float*)d_in[7];
    const float* b_ih1 = (const float*)d_in[8];
    const float* b_hh1 = (const float*)d_in[9];
    const float* W_out = (const float*)d_in[10];
    const float* b_out = (const float*)d_in[11];
    float* out = (float*)d_out;

    dim3 grid(B_TOTAL / 8);
    dim3 block(256);
    rnn_fused_kernel<<<grid, block, 0, stream>>>(x, h0, W_ih0, W_hh0, b_ih0, b_hh0,
                                                 W_ih1, W_hh1, b_ih1, b_hh1,
                                                 W_out, b_out, out);
}

// Round 2
// 730.579 us; speedup vs baseline: 1.6184x; 1.6184x over previous
//
#include <hip/hip_runtime.h>

#define T_LEN 1024
#define B_TOTAL 8192

typedef _Float16 half2v __attribute__((ext_vector_type(2)));

__device__ __forceinline__ float fast_tanh(float x) {
    // tanh(x) = 1 - 2/(exp(2x)+1); v_exp_f32 + v_rcp_f32, err ~1e-6.
    float e = __builtin_amdgcn_exp2f(x * 2.8853900817779268f); // 2*log2(e)
    float r = __builtin_amdgcn_rcpf(e + 1.0f);
    return fmaf(-2.0f, r, 1.0f);
}

__device__ __forceinline__ half2v to_h2(float lo, float hi) {
    half2v r;
    r.x = (_Float16)lo;
    r.y = (_Float16)hi;
    return r;
}

// One 32-lane group per batch element; lane i owns hidden unit i.
// Weights and replicated hidden state are f16 pairs consumed by
// v_dot2_f32_f16 (f32 accumulate): 16 insts per 32-dot, half the VGPRs.
__global__ __launch_bounds__(256, 4) void rnn_fused_kernel(
    const float* __restrict__ x,     const float* __restrict__ h0,
    const float* __restrict__ W_ih0, const float* __restrict__ W_hh0,
    const float* __restrict__ b_ih0, const float* __restrict__ b_hh0,
    const float* __restrict__ W_ih1, const float* __restrict__ W_hh1,
    const float* __restrict__ b_ih1, const float* __restrict__ b_hh1,
    const float* __restrict__ W_out, const float* __restrict__ b_out,
    float* __restrict__ out)
{
    // 40-f16 row stride (80B, 16B-aligned); 160B group stride rotates banks.
    __shared__ __align__(16) _Float16 hb[8][2][40];

    const int g = threadIdx.x >> 5;   // group (batch) within block
    const int i = threadIdx.x & 31;   // hidden unit owned by this lane
    const int b = blockIdx.x * 8 + g; // batch element

    // --- per-lane weight rows, f32 -> f16 pairs (one-time) ---
    half2v w0h[16], w1h[16], w2h[16];
#pragma unroll
    for (int j = 0; j < 16; ++j) {
        float2 a0 = ((const float2*)(W_hh0 + i * 32))[j];
        float2 a1 = ((const float2*)(W_ih1 + i * 32))[j];
        float2 a2 = ((const float2*)(W_hh1 + i * 32))[j];
        w0h[j] = to_h2(a0.x, a0.y);
        w1h[j] = to_h2(a1.x, a1.y);
        w2h[j] = to_h2(a2.x, a2.y);
    }
    const float wih0 = W_ih0[i];
    const float c0 = b_ih0[i] + b_hh0[i];
    const float c1 = b_ih1[i] + b_hh1[i];
    const float wo = W_out[i];
    const float bo = b_out[0];

    // --- replicated hidden state, f16 pairs (all 32 values per lane) ---
    half2v h1h[16] __attribute__((aligned(16)));
    half2v h2h[16] __attribute__((aligned(16)));
#pragma unroll
    for (int j = 0; j < 16; ++j) {
        float2 a = ((const float2*)(h0 + (size_t)b * 32))[j];
        float2 c = ((const float2*)(h0 + (size_t)(B_TOTAL + b) * 32))[j];
        h1h[j] = to_h2(a.x, a.y);
        h2h[j] = to_h2(c.x, c.y);
    }

    const float* xp = x + (size_t)b * T_LEN;
    float* yp = out + (size_t)b * T_LEN;
    float h1c = 0.0f, h2c = 0.0f; // this lane's own current h elements (f32)

    for (int t = 0; t < T_LEN; t += 4) {
        const float4 xv = *(const float4*)(xp + t);
        float y0, y1, y2, y3;
#pragma unroll
        for (int u = 0; u < 4; ++u) {
            const float xt = (u == 0) ? xv.x : (u == 1) ? xv.y : (u == 2) ? xv.z : xv.w;

            // ---- layer 1: a = c0 + x*wih0 + W_hh0[i,:] . h1 ----
            float a0 = fmaf(xt, wih0, c0), a1 = 0.f, a2 = 0.f, a3 = 0.f;
#pragma unroll
            for (int j = 0; j < 16; j += 4) {
                a0 = __builtin_amdgcn_fdot2(w0h[j + 0], h1h[j + 0], a0, false);
                a1 = __builtin_amdgcn_fdot2(w0h[j + 1], h1h[j + 1], a1, false);
                a2 = __builtin_amdgcn_fdot2(w0h[j + 2], h1h[j + 2], a2, false);
                a3 = __builtin_amdgcn_fdot2(w0h[j + 3], h1h[j + 3], a3, false);
            }
            h1c = fast_tanh((a0 + a1) + (a2 + a3));
            hb[g][0][i] = (_Float16)h1c; // publish own element (f16)

            // ---- layer 2 partial with OLD h2 (hides h1 LDS round-trip) ----
            float d0 = c1, d1 = 0.f, d2 = 0.f, d3 = 0.f;
#pragma unroll
            for (int j = 0; j < 16; j += 4) {
                d0 = __builtin_amdgcn_fdot2(w2h[j + 0], h2h[j + 0], d0, false);
                d1 = __builtin_amdgcn_fdot2(w2h[j + 1], h2h[j + 1], d1, false);
                d2 = __builtin_amdgcn_fdot2(w2h[j + 2], h2h[j + 2], d2, false);
                d3 = __builtin_amdgcn_fdot2(w2h[j + 3], h2h[j + 3], d3, false);
            }

            // ---- re-replicate h1 (wave-internal LDS FIFO; no barrier) ----
#pragma unroll
            for (int k = 0; k < 4; ++k)
                ((float4*)h1h)[k] = ((const float4*)&hb[g][0][0])[k];

#pragma unroll
            for (int j = 0; j < 16; j += 4) {
                d0 = __builtin_amdgcn_fdot2(w1h[j + 0], h1h[j + 0], d0, false);
                d1 = __builtin_amdgcn_fdot2(w1h[j + 1], h1h[j + 1], d1, false);
                d2 = __builtin_amdgcn_fdot2(w1h[j + 2], h1h[j + 2], d2, false);
                d3 = __builtin_amdgcn_fdot2(w1h[j + 3], h1h[j + 3], d3, false);
            }
            h2c = fast_tanh((d0 + d1) + (d2 + d3));
            hb[g][1][i] = (_Float16)h2c;

            // ---- re-replicate h2 FIRST (critical path), then y-reduce ----
#pragma unroll
            for (int k = 0; k < 4; ++k)
                ((float4*)h2h)[k] = ((const float4*)&hb[g][1][0])[k];

            // ---- y = W_out . h2_new + b_out (partial + xor-reduce) ----
            float p = wo * h2c;
            p += __shfl_xor(p, 1);
            p += __shfl_xor(p, 2);
            p += __shfl_xor(p, 4);
            p += __shfl_xor(p, 8);
            p += __shfl_xor(p, 16);
            const float yv = p + bo;
            if (u == 0) y0 = yv; else if (u == 1) y1 = yv; else if (u == 2) y2 = yv; else y3 = yv;
        }
        if (i == 0) {
            float4 yo; yo.x = y0; yo.y = y1; yo.z = y2; yo.w = y3;
            *(float4*)(yp + t) = yo;
        }
    }

    // final hidden states: h_state [2, B, 32] (f32, pre-quantization values)
    out[(size_t)B_TOTAL * T_LEN + (size_t)b * 32 + i] = h1c;
    out[(size_t)B_TOTAL * T_LEN + (size_t)(B_TOTAL + b) * 32 + i] = h2c;
}

extern "C" void kernel_launch(void* const* d_in, const int* in_sizes, int n_in,
                              void* d_out, int out_size, void* d_ws, size_t ws_size,
                              hipStream_t stream) {
    const float* x     = (const float*)d_in[0];
    const float* h0    = (const float*)d_in[1];
    const float* W_ih0 = (const float*)d_in[2];
    const float* W_hh0 = (const float*)d_in[3];
    const float* b_ih0 = (const float*)d_in[4];
    const float* b_hh0 = (const float*)d_in[5];
    const float* W_ih1 = (const float*)d_in[6];
    const float* W_hh1 = (const float*)d_in[7];
    const float* b_ih1 = (const float*)d_in[8];
    const float* b_hh1 = (const float*)d_in[9];
    const float* W_out = (const float*)d_in[10];
    const float* b_out = (const float*)d_in[11];
    float* out = (float*)d_out;

    dim3 grid(B_TOTAL / 8);
    dim3 block(256);
    rnn_fused_kernel<<<grid, block, 0, stream>>>(x, h0, W_ih0, W_hh0, b_ih0, b_hh0,
                                                 W_ih1, W_hh1, b_ih1, b_hh1,
                                                 W_out, b_out, out);
}

// Round 3
// 730.368 us; speedup vs baseline: 1.6189x; 1.0003x over previous
//
#include <hip/hip_runtime.h>

#define T_LEN 1024
#define B_TOTAL 8192

typedef _Float16 half2v __attribute__((ext_vector_type(2)));

__device__ __forceinline__ float fast_tanh(float x) {
    // tanh(x) = 1 - 2/(exp(2x)+1); v_exp_f32 + v_rcp_f32, err ~1e-6.
    float e = __builtin_amdgcn_exp2f(x * 2.8853900817779268f); // 2*log2(e)
    float r = __builtin_amdgcn_rcpf(e + 1.0f);
    return fmaf(-2.0f, r, 1.0f);
}

__device__ __forceinline__ half2v to_h2(float lo, float hi) {
    half2v r;
    r.x = (_Float16)lo;
    r.y = (_Float16)hi;
    return r;
}

// One 32-lane group per batch element; lane i owns hidden unit i.
// v_dot2_f32_f16 dots on f16 weight/state pairs, f32 accumulate.
// waves_per_eu pinned to 4 (grid supplies exactly 4 waves/SIMD) so the
// ~95-reg working set lives in true VGPRs - no accvgpr_read hops.
__global__
__attribute__((amdgpu_flat_work_group_size(256, 256), amdgpu_waves_per_eu(4, 4)))
void rnn_fused_kernel(
    const float* __restrict__ x,     const float* __restrict__ h0,
    const float* __restrict__ W_ih0, const float* __restrict__ W_hh0,
    const float* __restrict__ b_ih0, const float* __restrict__ b_hh0,
    const float* __restrict__ W_ih1, const float* __restrict__ W_hh1,
    const float* __restrict__ b_ih1, const float* __restrict__ b_hh1,
    const float* __restrict__ W_out, const float* __restrict__ b_out,
    float* __restrict__ out)
{
    // 40-f16 row stride (80B, 16B-aligned); 160B group stride rotates banks.
    __shared__ __align__(16) _Float16 hb[8][2][40];

    const int g = threadIdx.x >> 5;   // group (batch) within block
    const int i = threadIdx.x & 31;   // hidden unit owned by this lane
    const int b = blockIdx.x * 8 + g; // batch element

    // --- per-lane weight rows, f32 -> f16 pairs (one-time) ---
    half2v w0h[16], w1h[16], w2h[16];
#pragma unroll
    for (int j = 0; j < 16; ++j) {
        float2 a0 = ((const float2*)(W_hh0 + i * 32))[j];
        float2 a1 = ((const float2*)(W_ih1 + i * 32))[j];
        float2 a2 = ((const float2*)(W_hh1 + i * 32))[j];
        w0h[j] = to_h2(a0.x, a0.y);
        w1h[j] = to_h2(a1.x, a1.y);
        w2h[j] = to_h2(a2.x, a2.y);
    }
    const float wih0 = W_ih0[i];
    const float c0 = b_ih0[i] + b_hh0[i];
    const float c1 = b_ih1[i] + b_hh1[i];
    const float wo = W_out[i];
    const float bo = b_out[0];

    // --- replicated hidden state, f16 pairs (all 32 values per lane) ---
    half2v h1h[16] __attribute__((aligned(16)));
    half2v h2h[16] __attribute__((aligned(16)));
#pragma unroll
    for (int j = 0; j < 16; ++j) {
        float2 a = ((const float2*)(h0 + (size_t)b * 32))[j];
        float2 c = ((const float2*)(h0 + (size_t)(B_TOTAL + b) * 32))[j];
        h1h[j] = to_h2(a.x, a.y);
        h2h[j] = to_h2(c.x, c.y);
    }

    const float* xp = x + (size_t)b * T_LEN;
    float* yp = out + (size_t)b * T_LEN;
    float h1c = 0.0f, h2c = 0.0f; // this lane's own current h elements (f32)

    for (int t = 0; t < T_LEN; t += 4) {
        const float4 xv = *(const float4*)(xp + t);
        float y0, y1, y2, y3;
#pragma unroll
        for (int u = 0; u < 4; ++u) {
            const float xt = (u == 0) ? xv.x : (u == 1) ? xv.y : (u == 2) ? xv.z : xv.w;

            // ---- layer 1: a = c0 + x*wih0 + W_hh0[i,:] . h1 ----
            float a0 = fmaf(xt, wih0, c0), a1 = 0.f, a2 = 0.f, a3 = 0.f;
#pragma unroll
            for (int j = 0; j < 16; j += 4) {
                a0 = __builtin_amdgcn_fdot2(w0h[j + 0], h1h[j + 0], a0, false);
                a1 = __builtin_amdgcn_fdot2(w0h[j + 1], h1h[j + 1], a1, false);
                a2 = __builtin_amdgcn_fdot2(w0h[j + 2], h1h[j + 2], a2, false);
                a3 = __builtin_amdgcn_fdot2(w0h[j + 3], h1h[j + 3], a3, false);
            }
            h1c = fast_tanh((a0 + a1) + (a2 + a3));
            hb[g][0][i] = (_Float16)h1c; // publish own element (f16)

            // ---- layer 2 partial with OLD h2 (hides h1 LDS round-trip) ----
            float d0 = c1, d1 = 0.f, d2 = 0.f, d3 = 0.f;
#pragma unroll
            for (int j = 0; j < 16; j += 4) {
                d0 = __builtin_amdgcn_fdot2(w2h[j + 0], h2h[j + 0], d0, false);
                d1 = __builtin_amdgcn_fdot2(w2h[j + 1], h2h[j + 1], d1, false);
                d2 = __builtin_amdgcn_fdot2(w2h[j + 2], h2h[j + 2], d2, false);
                d3 = __builtin_amdgcn_fdot2(w2h[j + 3], h2h[j + 3], d3, false);
            }

            // ---- re-replicate h1 (wave-internal LDS FIFO; no barrier) ----
#pragma unroll
            for (int k = 0; k < 4; ++k)
                ((float4*)h1h)[k] = ((const float4*)&hb[g][0][0])[k];

#pragma unroll
            for (int j = 0; j < 16; j += 4) {
                d0 = __builtin_amdgcn_fdot2(w1h[j + 0], h1h[j + 0], d0, false);
                d1 = __builtin_amdgcn_fdot2(w1h[j + 1], h1h[j + 1], d1, false);
                d2 = __builtin_amdgcn_fdot2(w1h[j + 2], h1h[j + 2], d2, false);
                d3 = __builtin_amdgcn_fdot2(w1h[j + 3], h1h[j + 3], d3, false);
            }
            h2c = fast_tanh((d0 + d1) + (d2 + d3));
            hb[g][1][i] = (_Float16)h2c;

            // ---- re-replicate h2 FIRST (critical path), then y-reduce ----
#pragma unroll
            for (int k = 0; k < 4; ++k)
                ((float4*)h2h)[k] = ((const float4*)&hb[g][1][0])[k];

            // ---- y = W_out . h2_new + b_out (partial + xor-reduce) ----
            float p = wo * h2c;
            p += __shfl_xor(p, 1);
            p += __shfl_xor(p, 2);
            p += __shfl_xor(p, 4);
            p += __shfl_xor(p, 8);
            p += __shfl_xor(p, 16);
            const float yv = p + bo;
            if (u == 0) y0 = yv; else if (u == 1) y1 = yv; else if (u == 2) y2 = yv; else y3 = yv;
        }
        if (i == 0) {
            float4 yo; yo.x = y0; yo.y = y1; yo.z = y2; yo.w = y3;
            *(float4*)(yp + t) = yo;
        }
    }

    // final hidden states: h_state [2, B, 32] (f32, pre-quantization values)
    out[(size_t)B_TOTAL * T_LEN + (size_t)b * 32 + i] = h1c;
    out[(size_t)B_TOTAL * T_LEN + (size_t)(B_TOTAL + b) * 32 + i] = h2c;
}

extern "C" void kernel_launch(void* const* d_in, const int* in_sizes, int n_in,
                              void* d_out, int out_size, void* d_ws, size_t ws_size,
                              hipStream_t stream) {
    const float* x     = (const float*)d_in[0];
    const float* h0    = (const float*)d_in[1];
    const float* W_ih0 = (const float*)d_in[2];
    const float* W_hh0 = (const float*)d_in[3];
    const float* b_ih0 = (const float*)d_in[4];
    const float* b_hh0 = (const float*)d_in[5];
    const float* W_ih1 = (const float*)d_in[6];
    const float* W_hh1 = (const float*)d_in[7];
    const float* b_ih1 = (const float*)d_in[8];
    const float* b_hh1 = (const float*)d_in[9];
    const float* W_out = (const float*)d_in[10];
    const float* b_out = (const float*)d_in[11];
    float* out = (float*)d_out;

    dim3 grid(B_TOTAL / 8);
    dim3 block(256);
    rnn_fused_kernel<<<grid, block, 0, stream>>>(x, h0, W_ih0, W_hh0, b_ih0, b_hh0,
                                                 W_ih1, W_hh1, b_ih1, b_hh1,
                                                 W_out, b_out, out);
}

// Round 5
// 446.483 us; speedup vs baseline: 2.6482x; 1.6358x over previous
//
#include <hip/hip_runtime.h>

#define T_LEN 1024
#define B_TOTAL 8192

typedef _Float16 f16x8 __attribute__((ext_vector_type(8)));
typedef _Float16 f16x2 __attribute__((ext_vector_type(2)));
typedef float f32x4 __attribute__((ext_vector_type(4)));

__device__ __forceinline__ float fast_tanh(float x) {
    // tanh(x) = 1 - 2/(exp(2x)+1); v_exp_f32 + v_rcp_f32, err ~1e-6.
    float e = __builtin_amdgcn_exp2f(x * 2.8853900817779268f); // 2*log2(e)
    float r = __builtin_amdgcn_rcpf(e + 1.0f);
    return fmaf(-2.0f, r, 1.0f);
}

#define MFMA(a, b, c) __builtin_amdgcn_mfma_f32_16x16x32_f16((a), (b), (c), 0, 0, 0)

// One wave (64 lanes) per 16 batches. Batched-GEMM recurrence on MFMA:
//   D[m=unit][n=batch] = sum_k A[m,k]*B[n,k],  A = W (stationary), B = h.
// Layouts (m89-verified): D: n=lane&15, m=(lane>>4)*4+reg. A/B: row=lane&15,
// k=(lane>>4)*8+e (any consistent k-bijection works since shared by A and B).
// h transpose (D-layout -> B-layout) via LDS round-trip, asm-fenced (the
// round-4 failure was TBAA-legal reordering of LDS publish vs reload).
__global__ __launch_bounds__(64) void rnn_mfma_kernel(
    const float* __restrict__ x,     const float* __restrict__ h0,
    const float* __restrict__ W_ih0, const float* __restrict__ W_hh0,
    const float* __restrict__ b_ih0, const float* __restrict__ b_hh0,
    const float* __restrict__ W_ih1, const float* __restrict__ W_hh1,
    const float* __restrict__ b_ih1, const float* __restrict__ b_hh1,
    const float* __restrict__ W_out, const float* __restrict__ b_out,
    float* __restrict__ out)
{
    // 40-half row stride: 80B (16B-aligned rows; <=2-way bank alias = free)
    __shared__ __align__(16) _Float16 tb1[16][40];
    __shared__ __align__(16) _Float16 tb2[16][40];

    const int lane = threadIdx.x;          // 0..63
    const int bl   = lane & 15;            // local batch (n-index)
    const int hi   = lane >> 4;            // 0..3
    const int k0   = hi * 8;               // k offset in A/B frags
    const int m0   = hi * 4;               // m (unit) offset in D frags
    const int gb   = blockIdx.x * 16 + bl; // global batch

    // --- A-operand weight fragments (f16), A-row = out-unit ---
    f16x8 whh0_lo, whh0_hi, wih1_lo, wih1_hi, whh1_lo, whh1_hi, wout_f;
#pragma unroll
    for (int e = 0; e < 8; ++e) {
        whh0_lo[e] = (_Float16)W_hh0[bl * 32 + k0 + e];
        whh0_hi[e] = (_Float16)W_hh0[(16 + bl) * 32 + k0 + e];
        wih1_lo[e] = (_Float16)W_ih1[bl * 32 + k0 + e];
        wih1_hi[e] = (_Float16)W_ih1[(16 + bl) * 32 + k0 + e];
        whh1_lo[e] = (_Float16)W_hh1[bl * 32 + k0 + e];
        whh1_hi[e] = (_Float16)W_hh1[(16 + bl) * 32 + k0 + e];
        wout_f[e]  = (bl == 0) ? (_Float16)W_out[k0 + e] : (_Float16)0.0f;
    }

    // --- per-lane D-layout constants: units m0+r (lo) and 16+m0+r (hi) ---
    f32x4 c0lo, c0hi, c1lo, c1hi, wi0lo, wi0hi;
#pragma unroll
    for (int r = 0; r < 4; ++r) {
        const int u = m0 + r, uh = 16 + m0 + r;
        c0lo[r] = b_ih0[u]  + b_hh0[u];
        c0hi[r] = b_ih0[uh] + b_hh0[uh];
        c1lo[r] = b_ih1[u]  + b_hh1[u];
        c1hi[r] = b_ih1[uh] + b_hh1[uh];
        wi0lo[r] = W_ih0[u];
        wi0hi[r] = W_ih0[uh];
    }
    const float bo = b_out[0];
    const f32x4 zero4 = {0.f, 0.f, 0.f, 0.f};

    // --- B-operand state fragments: B[n=batch][k=unit], direct from h0 ---
    f16x8 Y1, Y2;
#pragma unroll
    for (int e = 0; e < 8; ++e) {
        Y1[e] = (_Float16)h0[(size_t)gb * 32 + k0 + e];
        Y2[e] = (_Float16)h0[(size_t)(B_TOTAL + gb) * 32 + k0 + e];
    }

    const float* xp = x + (size_t)gb * T_LEN;
    float* yp = out + (size_t)gb * T_LEN;
    float h1s[8], h2s[8];

    float4 xq = *(const float4*)(xp);
    for (int t = 0; t < T_LEN; t += 4) {
        // prefetch next x quad (hidden under ~4 steps of compute)
        const float4 xqn = (t + 4 < T_LEN) ? *(const float4*)(xp + t + 4) : xq;
        float yq0, yq1, yq2, yq3;
#pragma unroll
        for (int u = 0; u < 4; ++u) {
            const float xt = (u == 0) ? xq.x : (u == 1) ? xq.y : (u == 2) ? xq.z : xq.w;

            // ---- layer 1: D1 = W_hh0 . h1 + (c0 + wih0*x) ----
            f32x4 pre_lo, pre_hi;
#pragma unroll
            for (int r = 0; r < 4; ++r) {
                pre_lo[r] = fmaf(xt, wi0lo[r], c0lo[r]);
                pre_hi[r] = fmaf(xt, wi0hi[r], c0hi[r]);
            }
            f32x4 d1lo = MFMA(whh0_lo, Y1, pre_lo);
            f32x4 d1hi = MFMA(whh0_hi, Y1, pre_hi);
#pragma unroll
            for (int r = 0; r < 4; ++r) {
                h1s[r]     = fast_tanh(d1lo[r]);
                h1s[4 + r] = fast_tanh(d1hi[r]);
            }

            // ---- transpose h1 (D-layout -> B-layout) via LDS ----
            f16x2 p0; p0.x = (_Float16)h1s[0]; p0.y = (_Float16)h1s[1];
            f16x2 p1; p1.x = (_Float16)h1s[2]; p1.y = (_Float16)h1s[3];
            f16x2 p2; p2.x = (_Float16)h1s[4]; p2.y = (_Float16)h1s[5];
            f16x2 p3; p3.x = (_Float16)h1s[6]; p3.y = (_Float16)h1s[7];
            *(f16x2*)&tb1[bl][m0]        = p0;
            *(f16x2*)&tb1[bl][m0 + 2]    = p1;
            *(f16x2*)&tb1[bl][16 + m0]   = p2;
            *(f16x2*)&tb1[bl][16 + m0 + 2] = p3;
            asm volatile("" ::: "memory");

            // layer-2 recurrent part on OLD h2 overlaps the LDS turnaround
            f32x4 d2lo = MFMA(whh1_lo, Y2, c1lo);
            f32x4 d2hi = MFMA(whh1_hi, Y2, c1hi);

            const f16x8 Y1n = *(const f16x8*)&tb1[bl][k0];
            asm volatile("" ::: "memory");
            d2lo = MFMA(wih1_lo, Y1n, d2lo);
            d2hi = MFMA(wih1_hi, Y1n, d2hi);
#pragma unroll
            for (int r = 0; r < 4; ++r) {
                h2s[r]     = fast_tanh(d2lo[r]);
                h2s[4 + r] = fast_tanh(d2hi[r]);
            }

            // ---- transpose h2 via LDS ----
            f16x2 q0; q0.x = (_Float16)h2s[0]; q0.y = (_Float16)h2s[1];
            f16x2 q1; q1.x = (_Float16)h2s[2]; q1.y = (_Float16)h2s[3];
            f16x2 q2; q2.x = (_Float16)h2s[4]; q2.y = (_Float16)h2s[5];
            f16x2 q3; q3.x = (_Float16)h2s[6]; q3.y = (_Float16)h2s[7];
            *(f16x2*)&tb2[bl][m0]        = q0;
            *(f16x2*)&tb2[bl][m0 + 2]    = q1;
            *(f16x2*)&tb2[bl][16 + m0]   = q2;
            *(f16x2*)&tb2[bl][16 + m0 + 2] = q3;
            asm volatile("" ::: "memory");
            const f16x8 Y2n = *(const f16x8*)&tb2[bl][k0];
            asm volatile("" ::: "memory");

            // ---- y head: W_out as A-row 0; y[b] = D3[reg0] on hi==0 lanes ----
            const f32x4 d3 = MFMA(wout_f, Y2n, zero4);
            const float yv = d3[0] + bo;
            if (u == 0) yq0 = yv; else if (u == 1) yq1 = yv; else if (u == 2) yq2 = yv; else yq3 = yv;

            Y1 = Y1n;
            Y2 = Y2n;
        }
        if (hi == 0) {
            float4 yo; yo.x = yq0; yo.y = yq1; yo.z = yq2; yo.w = yq3;
            *(float4*)(yp + t) = yo;
        }
        xq = xqn;
    }

    // --- final hidden states: h_state [2, B, 32] (f32 trajectory values) ---
    float* hs = out + (size_t)B_TOTAL * T_LEN;
#pragma unroll
    for (int r = 0; r < 4; ++r) {
        hs[(size_t)gb * 32 + m0 + r]                       = h1s[r];
        hs[(size_t)gb * 32 + 16 + m0 + r]                  = h1s[4 + r];
        hs[(size_t)(B_TOTAL + gb) * 32 + m0 + r]           = h2s[r];
        hs[(size_t)(B_TOTAL + gb) * 32 + 16 + m0 + r]      = h2s[4 + r];
    }
}

extern "C" void kernel_launch(void* const* d_in, const int* in_sizes, int n_in,
                              void* d_out, int out_size, void* d_ws, size_t ws_size,
                              hipStream_t stream) {
    const float* x     = (const float*)d_in[0];
    const float* h0    = (const float*)d_in[1];
    const float* W_ih0 = (const float*)d_in[2];
    const float* W_hh0 = (const float*)d_in[3];
    const float* b_ih0 = (const float*)d_in[4];
    const float* b_hh0 = (const float*)d_in[5];
    const float* W_ih1 = (const float*)d_in[6];
    const float* W_hh1 = (const float*)d_in[7];
    const float* b_ih1 = (const float*)d_in[8];
    const float* b_hh1 = (const float*)d_in[9];
    const float* W_out = (const float*)d_in[10];
    const float* b_out = (const float*)d_in[11];
    float* out = (float*)d_out;

    dim3 grid(B_TOTAL / 16); // 512 waves, 1 wave/block, 16 batches each
    dim3 block(64);
    rnn_mfma_kernel<<<grid, block, 0, stream>>>(x, h0, W_ih0, W_hh0, b_ih0, b_hh0,
                                                W_ih1, W_hh1, b_ih1, b_hh1,
                                                W_out, b_out, out);
}

// Round 6
// 375.953 us; speedup vs baseline: 3.1451x; 1.1876x over previous
//
#include <hip/hip_runtime.h>

#define T_LEN 1024
#define B_TOTAL 8192

typedef _Float16 f16x8 __attribute__((ext_vector_type(8)));
typedef float f32x4 __attribute__((ext_vector_type(4)));

__device__ __forceinline__ float fast_tanh(float x) {
    // tanh(x) = 1 - 2/(exp(2x)+1); v_exp_f32 + v_rcp_f32, err ~1e-6.
    float e = __builtin_amdgcn_exp2f(x * 2.8853900817779268f); // 2*log2(e)
    float r = __builtin_amdgcn_rcpf(e + 1.0f);
    return fmaf(-2.0f, r, 1.0f);
}

#define MFMA(a, b, c) __builtin_amdgcn_mfma_f32_16x16x32_f16((a), (b), (c), 0, 0, 0)

// One wave per 16 batches; batched-GEMM recurrence fully in registers.
// Unit-relabeling trick: A-row m carries weight row u_lo(m)=8*(m>>2)+(m&3)
// (lo frag) / u_lo(m)+4 (hi frag), columns in identity order. Then lane
// (bl,g)'s D regs are storage slots {8g+r, 8g+4+r} == exactly the B-fragment
// k-slots {8g+e} this lane consumes next step. D -> tanh -> f16 cast -> B,
// zero cross-lane movement, zero LDS. Verified layouts from round 5:
// A/B row=lane&15, k=(lane>>4)*8+e; D n=lane&15, m=(lane>>4)*4+reg.
__global__ __launch_bounds__(64, 1) void rnn_mfma_kernel(
    const float* __restrict__ x,     const float* __restrict__ h0,
    const float* __restrict__ W_ih0, const float* __restrict__ W_hh0,
    const float* __restrict__ b_ih0, const float* __restrict__ b_hh0,
    const float* __restrict__ W_ih1, const float* __restrict__ W_hh1,
    const float* __restrict__ b_ih1, const float* __restrict__ b_hh1,
    const float* __restrict__ W_out, const float* __restrict__ b_out,
    float* __restrict__ out)
{
    const int lane = threadIdx.x;          // 0..63
    const int bl   = lane & 15;            // batch column (n-index)
    const int hi   = lane >> 4;            // lane quad group g
    const int s0   = hi * 8;               // storage-slot base (k and D regs)
    const int gb   = blockIdx.x * 16 + bl; // global batch

    const int ulo = 8 * (bl >> 2) + (bl & 3); // weight row for A-lo row bl
    const int uhi = ulo + 4;                  // weight row for A-hi row bl

    // --- stationary A fragments (weights, unit-permuted rows) ---
    f16x8 whh0_lo, whh0_hi, wih1_lo, wih1_hi, whh1_lo, whh1_hi, wout_f;
#pragma unroll
    for (int e = 0; e < 8; ++e) {
        whh0_lo[e] = (_Float16)W_hh0[ulo * 32 + s0 + e];
        whh0_hi[e] = (_Float16)W_hh0[uhi * 32 + s0 + e];
        wih1_lo[e] = (_Float16)W_ih1[ulo * 32 + s0 + e];
        wih1_hi[e] = (_Float16)W_ih1[uhi * 32 + s0 + e];
        whh1_lo[e] = (_Float16)W_hh1[ulo * 32 + s0 + e];
        whh1_hi[e] = (_Float16)W_hh1[uhi * 32 + s0 + e];
        wout_f[e]  = (bl == 0) ? (_Float16)W_out[s0 + e] : (_Float16)0.0f;
    }

    // --- per-lane D-layout constants: units s0+r (lo regs), s0+4+r (hi) ---
    f32x4 c0lo, c0hi, c1lo, c1hi, wi0lo, wi0hi;
#pragma unroll
    for (int r = 0; r < 4; ++r) {
        const int u = s0 + r, uh = s0 + 4 + r;
        c0lo[r] = b_ih0[u]  + b_hh0[u];
        c0hi[r] = b_ih0[uh] + b_hh0[uh];
        c1lo[r] = b_ih1[u]  + b_hh1[u];
        c1hi[r] = b_ih1[uh] + b_hh1[uh];
        wi0lo[r] = W_ih0[u];
        wi0hi[r] = W_ih0[uh];
    }
    const float bo = b_out[0];
    const f32x4 zero4 = {0.f, 0.f, 0.f, 0.f};

    // --- B-operand state fragments (identity storage order) ---
    f16x8 Y1, Y2;
#pragma unroll
    for (int e = 0; e < 8; ++e) {
        Y1[e] = (_Float16)h0[(size_t)gb * 32 + s0 + e];
        Y2[e] = (_Float16)h0[(size_t)(B_TOTAL + gb) * 32 + s0 + e];
    }

    const float* xp = x + (size_t)gb * T_LEN;
    float* yp = out + (size_t)gb * T_LEN;
    float h1f[8], h2f[8]; // f32 trajectory values (for final h_state)

    float4 xq = *(const float4*)(xp);
    for (int t = 0; t < T_LEN; t += 4) {
        const float4 xqn = (t + 4 < T_LEN) ? *(const float4*)(xp + t + 4) : xq;
        float yq0, yq1, yq2, yq3;
#pragma unroll
        for (int u = 0; u < 4; ++u) {
            const float xt = (u == 0) ? xq.x : (u == 1) ? xq.y : (u == 2) ? xq.z : xq.w;

            // ---- layer 1: D1 = W_hh0 . h1 + (c0 + wih0*x) ----
            f32x4 pre_lo, pre_hi;
#pragma unroll
            for (int r = 0; r < 4; ++r) {
                pre_lo[r] = fmaf(xt, wi0lo[r], c0lo[r]);
                pre_hi[r] = fmaf(xt, wi0hi[r], c0hi[r]);
            }
            const f32x4 d1lo = MFMA(whh0_lo, Y1, pre_lo);
            const f32x4 d1hi = MFMA(whh0_hi, Y1, pre_hi);
            // layer-2 recurrent half on OLD h2 overlaps the d1->tanh chain
            f32x4 d2lo = MFMA(whh1_lo, Y2, c1lo);
            f32x4 d2hi = MFMA(whh1_hi, Y2, c1hi);

            // ---- h1 = tanh(D1); cast straight into next B fragment ----
            f16x8 Y1n;
#pragma unroll
            for (int r = 0; r < 4; ++r) {
                h1f[r]     = fast_tanh(d1lo[r]);
                h1f[4 + r] = fast_tanh(d1hi[r]);
                Y1n[r]     = (_Float16)h1f[r];
                Y1n[4 + r] = (_Float16)h1f[4 + r];
            }
            d2lo = MFMA(wih1_lo, Y1n, d2lo);
            d2hi = MFMA(wih1_hi, Y1n, d2hi);

            f16x8 Y2n;
#pragma unroll
            for (int r = 0; r < 4; ++r) {
                h2f[r]     = fast_tanh(d2lo[r]);
                h2f[4 + r] = fast_tanh(d2hi[r]);
                Y2n[r]     = (_Float16)h2f[r];
                Y2n[4 + r] = (_Float16)h2f[4 + r];
            }

            // ---- y head: W_out in A-row 0; y[b] = D3[m=0][n=b] ----
            const f32x4 d3 = MFMA(wout_f, Y2n, zero4);
            const float yv = d3[0] + bo;
            if (u == 0) yq0 = yv; else if (u == 1) yq1 = yv; else if (u == 2) yq2 = yv; else yq3 = yv;

            Y1 = Y1n;
            Y2 = Y2n;
        }
        if (hi == 0) {
            float4 yo; yo.x = yq0; yo.y = yq1; yo.z = yq2; yo.w = yq3;
            *(float4*)(yp + t) = yo;
        }
        xq = xqn;
    }

    // --- final hidden states: h_state [2, B, 32], storage order = unit ---
    float* hs = out + (size_t)B_TOTAL * T_LEN;
#pragma unroll
    for (int r = 0; r < 4; ++r) {
        hs[(size_t)gb * 32 + s0 + r]                      = h1f[r];
        hs[(size_t)gb * 32 + s0 + 4 + r]                  = h1f[4 + r];
        hs[(size_t)(B_TOTAL + gb) * 32 + s0 + r]          = h2f[r];
        hs[(size_t)(B_TOTAL + gb) * 32 + s0 + 4 + r]      = h2f[4 + r];
    }
}

extern "C" void kernel_launch(void* const* d_in, const int* in_sizes, int n_in,
                              void* d_out, int out_size, void* d_ws, size_t ws_size,
                              hipStream_t stream) {
    const float* x     = (const float*)d_in[0];
    const float* h0    = (const float*)d_in[1];
    const float* W_ih0 = (const float*)d_in[2];
    const float* W_hh0 = (const float*)d_in[3];
    const float* b_ih0 = (const float*)d_in[4];
    const float* b_hh0 = (const float*)d_in[5];
    const float* W_ih1 = (const float*)d_in[6];
    const float* W_hh1 = (const float*)d_in[7];
    const float* b_ih1 = (const float*)d_in[8];
    const float* b_hh1 = (const float*)d_in[9];
    const float* W_out = (const float*)d_in[10];
    const float* b_out = (const float*)d_in[11];
    float* out = (float*)d_out;

    dim3 grid(B_TOTAL / 16); // 512 waves, 1 wave/block, 16 batches each
    dim3 block(64);
    rnn_mfma_kernel<<<grid, block, 0, stream>>>(x, h0, W_ih0, W_hh0, b_ih0, b_hh0,
                                                W_ih1, W_hh1, b_ih1, b_hh1,
                                                W_out, b_out, out);
}

// Round 7
// 358.195 us; speedup vs baseline: 3.3010x; 1.0496x over previous
//
#include <hip/hip_runtime.h>

#define T_LEN 1024
#define B_TOTAL 8192

typedef _Float16 f16x8 __attribute__((ext_vector_type(8)));
typedef float f32x4 __attribute__((ext_vector_type(4)));

__device__ __forceinline__ float fast_tanh(float x) {
    // tanh(x) = 1 - 2/(exp(2x)+1); v_exp_f32 + v_rcp_f32, err ~1e-6.
    float e = __builtin_amdgcn_exp2f(x * 2.8853900817779268f); // 2*log2(e)
    float r = __builtin_amdgcn_rcpf(e + 1.0f);
    return fmaf(-2.0f, r, 1.0f);
}

#define MFMA(a, b, c) __builtin_amdgcn_mfma_f32_16x16x32_f16((a), (b), (c), 0, 0, 0)

// Two-wave pipeline per block of 16 batches:
//   wave0 (producer): h1 recurrence (layer 1), publishes h1(t) to LDS.
//   wave1 (consumer): h2 recurrence (layer 2) + y head + stores.
// One s_barrier per step, double-buffered handoff; each wave's per-step
// VALU issue is ~half of round 6's single-wave chain, and the two waves'
// stalls overlap. 512 blocks x 2 waves = 1024 waves = 1 per SIMD.
// Unit-relabeling (round-6-verified): A-row m <- weight row 8*(m>>2)+(m&3)
// (lo) / +4 (hi); then lane (bl,g)'s D regs are storage slots {8g+r,8g+4+r}
// = exactly the B-fragment k-slots it consumes -> no transpose anywhere.
__global__ __launch_bounds__(128, 1) void rnn_pipe_kernel(
    const float* __restrict__ x,     const float* __restrict__ h0,
    const float* __restrict__ W_ih0, const float* __restrict__ W_hh0,
    const float* __restrict__ b_ih0, const float* __restrict__ b_hh0,
    const float* __restrict__ W_ih1, const float* __restrict__ W_hh1,
    const float* __restrict__ b_ih1, const float* __restrict__ b_hh1,
    const float* __restrict__ W_out, const float* __restrict__ b_out,
    float* __restrict__ out)
{
    // 40-half row stride (80B): 16B-aligned, <=2-way bank alias (free).
    __shared__ __align__(16) _Float16 h1buf[2][16][40];

    const int tid  = threadIdx.x;
    const int wid  = tid >> 6;            // 0 = producer, 1 = consumer
    const int lane = tid & 63;
    const int bl   = lane & 15;           // batch column (n-index / A-row)
    const int hi   = lane >> 4;           // lane quad g
    const int s0   = hi * 8;              // storage-slot base
    const int gb   = blockIdx.x * 16 + bl;

    const int ulo = 8 * (bl >> 2) + (bl & 3); // weight row for A-lo row bl
    const int uhi = ulo + 4;

    if (wid == 0) {
        // ================= producer: layer 1 =================
        f16x8 whh0_lo, whh0_hi;
#pragma unroll
        for (int e = 0; e < 8; ++e) {
            whh0_lo[e] = (_Float16)W_hh0[ulo * 32 + s0 + e];
            whh0_hi[e] = (_Float16)W_hh0[uhi * 32 + s0 + e];
        }
        f32x4 c0lo, c0hi, wi0lo, wi0hi;
#pragma unroll
        for (int r = 0; r < 4; ++r) {
            const int u = s0 + r, uh = s0 + 4 + r;
            c0lo[r] = b_ih0[u]  + b_hh0[u];
            c0hi[r] = b_ih0[uh] + b_hh0[uh];
            wi0lo[r] = W_ih0[u];
            wi0hi[r] = W_ih0[uh];
        }
        f16x8 Y1;
#pragma unroll
        for (int e = 0; e < 8; ++e)
            Y1[e] = (_Float16)h0[(size_t)gb * 32 + s0 + e];

        const float* xp = x + (size_t)gb * T_LEN;
        float h1f[8];

        float4 xq = *(const float4*)(xp);
        for (int t = 0; t < T_LEN; t += 4) {
            const float4 xqn = (t + 4 < T_LEN) ? *(const float4*)(xp + t + 4) : xq;
#pragma unroll
            for (int u = 0; u < 4; ++u) {
                const float xt = (u == 0) ? xq.x : (u == 1) ? xq.y : (u == 2) ? xq.z : xq.w;
                f32x4 pre_lo, pre_hi;
#pragma unroll
                for (int r = 0; r < 4; ++r) {
                    pre_lo[r] = fmaf(xt, wi0lo[r], c0lo[r]);
                    pre_hi[r] = fmaf(xt, wi0hi[r], c0hi[r]);
                }
                const f32x4 d1lo = MFMA(whh0_lo, Y1, pre_lo);
                const f32x4 d1hi = MFMA(whh0_hi, Y1, pre_hi);
                f16x8 Y1n;
#pragma unroll
                for (int r = 0; r < 4; ++r) {
                    h1f[r]     = fast_tanh(d1lo[r]);
                    h1f[4 + r] = fast_tanh(d1hi[r]);
                    Y1n[r]     = (_Float16)h1f[r];
                    Y1n[4 + r] = (_Float16)h1f[4 + r];
                }
                // publish h1(t): one 16B LDS store at the consumer's B-slots
                *(f16x8*)&h1buf[u & 1][bl][s0] = Y1n;
                asm volatile("s_waitcnt lgkmcnt(0)" ::: "memory");
                __builtin_amdgcn_s_barrier();
                Y1 = Y1n;
            }
            xq = xqn;
        }
        // final h1 -> h_state[0]
        float* hs = out + (size_t)B_TOTAL * T_LEN;
#pragma unroll
        for (int r = 0; r < 4; ++r) {
            hs[(size_t)gb * 32 + s0 + r]     = h1f[r];
            hs[(size_t)gb * 32 + s0 + 4 + r] = h1f[4 + r];
        }
    } else {
        // ================= consumer: layer 2 + head =================
        f16x8 wih1_lo, wih1_hi, whh1_lo, whh1_hi, wout_f;
#pragma unroll
        for (int e = 0; e < 8; ++e) {
            wih1_lo[e] = (_Float16)W_ih1[ulo * 32 + s0 + e];
            wih1_hi[e] = (_Float16)W_ih1[uhi * 32 + s0 + e];
            whh1_lo[e] = (_Float16)W_hh1[ulo * 32 + s0 + e];
            whh1_hi[e] = (_Float16)W_hh1[uhi * 32 + s0 + e];
            wout_f[e]  = (bl == 0) ? (_Float16)W_out[s0 + e] : (_Float16)0.0f;
        }
        f32x4 c1lo, c1hi;
#pragma unroll
        for (int r = 0; r < 4; ++r) {
            const int u = s0 + r, uh = s0 + 4 + r;
            c1lo[r] = b_ih1[u]  + b_hh1[u];
            c1hi[r] = b_ih1[uh] + b_hh1[uh];
        }
        const float bo = b_out[0];
        const f32x4 zero4 = {0.f, 0.f, 0.f, 0.f};

        f16x8 Y2;
#pragma unroll
        for (int e = 0; e < 8; ++e)
            Y2[e] = (_Float16)h0[(size_t)(B_TOTAL + gb) * 32 + s0 + e];

        float* yp = out + (size_t)gb * T_LEN;
        float h2f[8];

        for (int t = 0; t < T_LEN; t += 4) {
            float yq0, yq1, yq2, yq3;
#pragma unroll
            for (int u = 0; u < 4; ++u) {
                // recurrent half on own (old) h2 - issued before the handoff
                f32x4 d2lo = MFMA(whh1_lo, Y2, c1lo);
                f32x4 d2hi = MFMA(whh1_hi, Y2, c1hi);

                __builtin_amdgcn_s_barrier();
                asm volatile("" ::: "memory");
                const f16x8 Y1n = *(const f16x8*)&h1buf[u & 1][bl][s0];
                asm volatile("" ::: "memory");

                d2lo = MFMA(wih1_lo, Y1n, d2lo);
                d2hi = MFMA(wih1_hi, Y1n, d2hi);
                f16x8 Y2n;
#pragma unroll
                for (int r = 0; r < 4; ++r) {
                    h2f[r]     = fast_tanh(d2lo[r]);
                    h2f[4 + r] = fast_tanh(d2hi[r]);
                    Y2n[r]     = (_Float16)h2f[r];
                    Y2n[4 + r] = (_Float16)h2f[4 + r];
                }

                // y head: W_out in A-row 0 -> y[bl] = D[m=0][bl] (hi==0, reg0)
                const f32x4 d3 = MFMA(wout_f, Y2n, zero4);
                const float yv = d3[0] + bo;
                if (u == 0) yq0 = yv; else if (u == 1) yq1 = yv; else if (u == 2) yq2 = yv; else yq3 = yv;

                Y2 = Y2n;
            }
            if (hi == 0) {
                float4 yo; yo.x = yq0; yo.y = yq1; yo.z = yq2; yo.w = yq3;
                *(float4*)(yp + t) = yo;
            }
        }
        // final h2 -> h_state[1]
        float* hs = out + (size_t)B_TOTAL * T_LEN;
#pragma unroll
        for (int r = 0; r < 4; ++r) {
            hs[(size_t)(B_TOTAL + gb) * 32 + s0 + r]     = h2f[r];
            hs[(size_t)(B_TOTAL + gb) * 32 + s0 + 4 + r] = h2f[4 + r];
        }
    }
}

extern "C" void kernel_launch(void* const* d_in, const int* in_sizes, int n_in,
                              void* d_out, int out_size, void* d_ws, size_t ws_size,
                              hipStream_t stream) {
    const float* x     = (const float*)d_in[0];
    const float* h0    = (const float*)d_in[1];
    const float* W_ih0 = (const float*)d_in[2];
    const float* W_hh0 = (const float*)d_in[3];
    const float* b_ih0 = (const float*)d_in[4];
    const float* b_hh0 = (const float*)d_in[5];
    const float* W_ih1 = (const float*)d_in[6];
    const float* W_hh1 = (const float*)d_in[7];
    const float* b_ih1 = (const float*)d_in[8];
    const float* b_hh1 = (const float*)d_in[9];
    const float* W_out = (const float*)d_in[10];
    const float* b_out = (const float*)d_in[11];
    float* out = (float*)d_out;

    dim3 grid(B_TOTAL / 16); // 512 blocks x 2 waves = 1024 waves (1/SIMD)
    dim3 block(128);
    rnn_pipe_kernel<<<grid, block, 0, stream>>>(x, h0, W_ih0, W_hh0, b_ih0, b_hh0,
                                                W_ih1, W_hh1, b_ih1, b_hh1,
                                                W_out, b_out, out);
}